// Round 1
// baseline (431.994 us; speedup 1.0000x reference)
//
#include <hip/hip_runtime.h>

// out[b,s,f] = sx[b,s] * sk[f] * sum_d qx[b,s,d] * qk[d,f]
// Exact int32 accumulation via v_mfma_i32_16x16x64_i8.
//
// R3 changes (prep-pipeline round; GEMM kept as control):
//  * Tile layout At/Bt: [tile16][kc64][r16][64B] (was [tile16][ks16][r16][16B]).
//    Producer writes are now 64B-sector-aligned (quant_act) or fully
//    contiguous 1KB/wave (wk_quant) -- kills cross-XCD partial-line RMW
//    (rows of one tile come from 16 consecutive blocks = all 8 XCDs).
//    GEMM staging source addresses re-permuted to match; per-wave global
//    reads remain contiguous 1KB and the LDS image is bit-identical.
//  * 5 dispatches -> 3: W-amax fused into the quant_act dispatch (overlaps
//    the independent X and W HBM streams), scale-combine fused into
//    wk_quant's prologue (W loads issued before the combine barrier).
//  * W-amax reads float4 (was scalar dword).

#define M_DIM 8192
#define K_DIM 4096
#define N_DIM 4096

typedef int v4i __attribute__((ext_vector_type(4)));
typedef __attribute__((address_space(3))) void lds_void_t;
typedef const __attribute__((address_space(1))) void g_void_t;

// ---------------- fused: W column-amax partials (blocks 0..127)  +
//                  activation row quant (blocks 128..8319) ----------------
__global__ void fused_qa(const float* __restrict__ X,
                         signed char* __restrict__ At,
                         float* __restrict__ sx,
                         const float* __restrict__ W,
                         float* __restrict__ part) {
  const int t = threadIdx.x;
  __shared__ float red[4];
  __shared__ float s_inv;
  __shared__ __align__(16) unsigned int shuf[1024];

  if (blockIdx.x < 128) {
    // per-column |max| over a 128-row slab of W, float4-wide.
    // part[slab][f]: 32 slabs x 4096 floats = 512 KB.
    const int f4 = (blockIdx.x & 3) * 256 + t;  // float4 column 0..1023
    const int slab = blockIdx.x >> 2;           // 0..31
    const float4* p = (const float4*)W + (size_t)slab * 128 * 1024 + f4;
    float4 a0 = {0.f, 0.f, 0.f, 0.f}, a1 = {0.f, 0.f, 0.f, 0.f};
#pragma unroll 8
    for (int i = 0; i < 64; ++i) {
      float4 u = p[(size_t)(2 * i) * 1024];
      float4 v = p[(size_t)(2 * i + 1) * 1024];
      a0.x = fmaxf(a0.x, fabsf(u.x));
      a0.y = fmaxf(a0.y, fabsf(u.y));
      a0.z = fmaxf(a0.z, fabsf(u.z));
      a0.w = fmaxf(a0.w, fabsf(u.w));
      a1.x = fmaxf(a1.x, fabsf(v.x));
      a1.y = fmaxf(a1.y, fabsf(v.y));
      a1.z = fmaxf(a1.z, fabsf(v.z));
      a1.w = fmaxf(a1.w, fabsf(v.w));
    }
    float4 r;
    r.x = fmaxf(a0.x, a1.x);
    r.y = fmaxf(a0.y, a1.y);
    r.z = fmaxf(a0.z, a1.z);
    r.w = fmaxf(a0.w, a1.w);
    ((float4*)part)[(size_t)slab * 1024 + f4] = r;
    return;
  }

  // ---- activation path: one row per block ----
  const int row = blockIdx.x - 128;
  const float* xr = X + (size_t)row * K_DIM;
  float4 v[4];
  float am = 0.f;
#pragma unroll
  for (int c = 0; c < 4; ++c) {
    v[c] = ((const float4*)xr)[c * 256 + t];  // coalesced 16B/lane
    am = fmaxf(am, fmaxf(fmaxf(fabsf(v[c].x), fabsf(v[c].y)),
                         fmaxf(fabsf(v[c].z), fabsf(v[c].w))));
  }
#pragma unroll
  for (int off = 32; off > 0; off >>= 1)
    am = fmaxf(am, __shfl_down(am, off));
  if ((t & 63) == 0) red[t >> 6] = am;
  __syncthreads();
  if (t == 0) {
    float m = fmaxf(fmaxf(red[0], red[1]), fmaxf(red[2], red[3]));
    float scale = fmaxf(m, 1e-6f) / 127.0f;  // matches ref
    sx[row] = scale;
    s_inv = 1.0f / scale;
  }
  __syncthreads();
  const float inv = s_inv;
#pragma unroll
  for (int c = 0; c < 4; ++c) {
    int q0 = (int)fminf(fmaxf(rintf(v[c].x * inv), -127.f), 127.f);
    int q1 = (int)fminf(fmaxf(rintf(v[c].y * inv), -127.f), 127.f);
    int q2 = (int)fminf(fmaxf(rintf(v[c].z * inv), -127.f), 127.f);
    int q3 = (int)fminf(fmaxf(rintf(v[c].w * inv), -127.f), 127.f);
    shuf[c * 256 + t] = (q0 & 255) | ((q1 & 255) << 8) | ((q2 & 255) << 16) | (q3 << 24);
  }
  __syncthreads();
  // thread t emits the row's 16B k-slice ks=t into the 64B-interleaved tile:
  // addr(row,k) = (row>>4)*65536 + (k>>6)*1024 + (row&15)*64 + (k&63)
  v4i w = *(const v4i*)&shuf[t * 4];
  signed char* dst = At + (size_t)(row >> 4) * 65536 + (t >> 2) * 1024 +
                     (row & 15) * 64 + (t & 3) * 16;
  *(v4i*)dst = w;
}

// ---------------- weight quant (+ inline scale combine) into Bt ----------------
__global__ void wk_quant(const float* __restrict__ W,
                         const float* __restrict__ part,
                         signed char* __restrict__ Bt,
                         float* __restrict__ sk) {
  const int bx = blockIdx.x;
  const int f0 = (bx & 63) * 64;
  const int d0 = (bx >> 6) * 64;
  const int t = threadIdx.x;
  const int fl4 = t & 15;   // float4-column within the 64-f stripe
  const int dl0 = t >> 4;   // row group 0..15
  __shared__ __align__(16) signed char tile[64 * 80];  // [f_local][d], stride 80 (16-aligned)
  __shared__ float sl_inv[64];

  // issue the big W loads first; the scale-combine below hides under them
  float4 wv[4];
#pragma unroll
  for (int c = 0; c < 4; ++c) {
    const int dl = c * 16 + dl0;
    wv[c] = ((const float4*)W)[(size_t)(d0 + dl) * 1024 + (f0 >> 2) + fl4];
  }
  // combine 32 slab partials -> per-column scale (threads 0..63)
  if (t < 64) {
    const int f = f0 + t;
    float m = 0.f;
#pragma unroll
    for (int s = 0; s < 32; ++s) m = fmaxf(m, part[(size_t)s * 4096 + f]);
    const float scale = fmaxf(m, 1e-6f) / 127.0f;
    if (bx < 64) sk[f] = scale;  // d0==0 blocks publish sk exactly once
    sl_inv[t] = 1.0f / scale;
  }
  __syncthreads();
  const float4 inv4 = *(const float4*)&sl_inv[fl4 * 4];
#pragma unroll
  for (int c = 0; c < 4; ++c) {
    const int dl = c * 16 + dl0;
    tile[(fl4 * 4 + 0) * 80 + dl] =
        (signed char)(int)fminf(fmaxf(rintf(wv[c].x * inv4.x), -127.f), 127.f);
    tile[(fl4 * 4 + 1) * 80 + dl] =
        (signed char)(int)fminf(fmaxf(rintf(wv[c].y * inv4.y), -127.f), 127.f);
    tile[(fl4 * 4 + 2) * 80 + dl] =
        (signed char)(int)fminf(fmaxf(rintf(wv[c].z * inv4.z), -127.f), 127.f);
    tile[(fl4 * 4 + 3) * 80 + dl] =
        (signed char)(int)fminf(fmaxf(rintf(wv[c].w * inv4.w), -127.f), 127.f);
  }
  __syncthreads();
  // one 16B chunk per thread; wave writes a contiguous (lane-permuted) 1KB
  const int frow = t >> 2;
  const int ksl = t & 3;
  v4i w = *(const v4i*)&tile[frow * 80 + ksl * 16];
  signed char* dst = Bt + (size_t)((f0 + frow) >> 4) * 65536 + (d0 >> 6) * 1024 +
                     (frow & 15) * 64 + ksl * 16;
  *(v4i*)dst = w;
}

// ---------------- int8 GEMM: 128x128 tile, BK=128, 4 waves, 16x16x64 i8 MFMA ----
// Unchanged from R2 except the staging SOURCE address permutation for the
// 64B-interleaved global layout; the LDS image (and thus fragment reads,
// MFMA, epilogue) is bit-identical to R2.
__global__ __launch_bounds__(256, 2) void gemm_i8(
    const signed char* __restrict__ At, const signed char* __restrict__ Bt,
    const float* __restrict__ sx, const float* __restrict__ sk,
    float* __restrict__ C) {
  const int n0 = blockIdx.x * 128;
  const int m0 = blockIdx.y * 128;
  const int t = threadIdx.x;
  const int lane = t & 63;
  const int wave = t >> 6;
  const int wm = (wave >> 1) * 64;  // wave's 64x64 sub-tile
  const int wn = (wave & 1) * 64;
  const int lrow = lane & 15;
  const int lq = lane >> 4;

  // lds chunk c (c=0..1023): mt_i=c>>7, s=(c>>6)&1, lane=c&63 -> holds
  // row mt_i*16+(lane&15), k-slice s*64+(lane>>4)*16 of the current K-block.
  __shared__ __align__(16) signed char lds[32768];
  signed char* lA = lds;
  signed char* lB = lds + 16384;

  v4i acc[4][4];
#pragma unroll
  for (int i = 0; i < 4; ++i)
#pragma unroll
    for (int j = 0; j < 4; ++j) acc[i][j] = (v4i){0, 0, 0, 0};

  const signed char* Abase = At + (size_t)(m0 >> 4) * 65536;
  const signed char* Bbase = Bt + (size_t)(n0 >> 4) * 65536;

  // fragment read bases: addr = mt_i*2048 + s*1024 + lane*16 (contiguous per read)
  const int la = ((wave >> 1) * 4) * 2048 + lane * 16;
  const int lb = ((wave & 1) * 4) * 2048 + lane * 16;

  for (int kb = 0; kb < K_DIM; kb += 128) {
    const int kofs = kb * 16;  // == (kb>>6)*1024 bytes into each tile-row
    // stage 16KB A + 16KB B: every wave-instr reads a contiguous 1KB
    // (lane-permuted for the [kc64][r][64] interleave)
#pragma unroll
    for (int j = 0; j < 4; ++j) {
      const int c = j * 256 + t;
      const int mt_i = c >> 7;
      const int off = ((c >> 6) & 1) * 1024 + (c & 15) * 64 + ((c >> 4) & 3) * 16;
      __builtin_amdgcn_global_load_lds(
          (g_void_t*)(Abase + (size_t)mt_i * 65536 + kofs + off),
          (lds_void_t*)(lA + c * 16), 16, 0, 0);
      __builtin_amdgcn_global_load_lds(
          (g_void_t*)(Bbase + (size_t)mt_i * 65536 + kofs + off),
          (lds_void_t*)(lB + c * 16), 16, 0, 0);
    }
    __syncthreads();
#pragma unroll
    for (int s = 0; s < 2; ++s) {  // two K=64 steps per staging round
      v4i af[4], bf[4];
#pragma unroll
      for (int i = 0; i < 4; ++i) af[i] = *(const v4i*)(lA + la + i * 2048 + s * 1024);
#pragma unroll
      for (int i = 0; i < 4; ++i) bf[i] = *(const v4i*)(lB + lb + i * 2048 + s * 1024);
#pragma unroll
      for (int mi = 0; mi < 4; ++mi)
#pragma unroll
        for (int ni = 0; ni < 4; ++ni)
          acc[mi][ni] =
              __builtin_amdgcn_mfma_i32_16x16x64_i8(af[mi], bf[ni], acc[mi][ni], 0, 0, 0);
    }
    __syncthreads();
  }

  // epilogue: C/D layout col=lane&15, row=(lane>>4)*4+reg (dtype-independent)
#pragma unroll
  for (int mi = 0; mi < 4; ++mi) {
#pragma unroll
    for (int ni = 0; ni < 4; ++ni) {
      const int gn = n0 + wn + ni * 16 + lrow;
      const float skv = sk[gn];
#pragma unroll
      for (int r = 0; r < 4; ++r) {
        const int gm = m0 + wm + mi * 16 + lq * 4 + r;
        C[(size_t)gm * N_DIM + gn] = (float)acc[mi][ni][r] * sx[gm] * skv;
      }
    }
  }
}

// ---------------- launch ----------------
extern "C" void kernel_launch(void* const* d_in, const int* in_sizes, int n_in,
                              void* d_out, int out_size, void* d_ws, size_t ws_size,
                              hipStream_t stream) {
  const float* X = (const float*)d_in[0];  // [4,2048,4096] fp32
  const float* W = (const float*)d_in[1];  // [4096,4096] fp32
  float* out = (float*)d_out;              // [4,2048,4096] fp32
  char* ws = (char*)d_ws;

  signed char* At = (signed char*)ws;              // 32 MB  tiled A
  signed char* Bt = (signed char*)(ws + 33554432); // 16 MB  tiled B
  float* sx = (float*)(ws + 50331648);             // 32 KB
  float* sk = (float*)(ws + 50364416);             // 16 KB
  float* part = (float*)(ws + 50380800);           // 512 KB (32 slabs x 4096)

  fused_qa<<<8320, 256, 0, stream>>>(X, At, sx, W, part);     // 128 amax + 8192 rows
  wk_quant<<<4096, 256, 0, stream>>>(W, part, Bt, sk);
  gemm_i8<<<dim3(N_DIM / 128, M_DIM / 128), 256, 0, stream>>>(At, Bt, sx, sk, out);
}